// Round 7
// baseline (312.642 us; speedup 1.0000x reference)
//
#include <hip/hip_runtime.h>
#include <math.h>

// B=4,H=16 (NH=64), S=2048, D=64, fp32 in/out.
// scores = (Q@K^T)*4096, softmax, @V.
// f16 2-plane split: S = qh*kh + qh*km(lo) + qm(lo)*kh (err ~2^-22),
// PV = f16(P) x f16(V). Q scaled by 4096*log2e/64 (in-kernel split),
// K by 64 (prepass), V transposed to f16 (prepass, fused into one launch).
// Round 13: round-6 skeleton (register staging, 2 barriers/tile -- verified
// r0/r1/r2/r6) with BM 128->64: 4 waves x 16 q-rows. Halves per-wave
// register state (aq 16, S 16, Oacc 16, ap 4; total ~100 incl AGPRs vs
// ~160 in r6) -> 4-5 wave slots/SIMD in the unified 512-reg file (r6
// occupancy was capped at ~2 blocks/CU by VGPR+AGPR, not LDS).
// Grid 2048 blocks; LDS 24576B. Register-direct PV via mfma_f32_16x16x16f16
// (B-frag k=4g+e == S^T layout; P never touches LDS); O^T accumulator
// (lane-local alpha, float4 stores).

#define S_LEN 2048
#define D_DIM 64
#define NH 64
#define BM 64
#define BN 64
#define QTILES (S_LEN / BM)   // 32
#define KTILES (S_LEN / BN)   // 32

typedef unsigned short u16;
typedef unsigned int u32;
typedef _Float16 f16;
typedef __attribute__((ext_vector_type(4))) _Float16 f16x4;
typedef __attribute__((ext_vector_type(8))) _Float16 f16x8;
typedef __attribute__((ext_vector_type(2))) __fp16 fp16x2;
typedef __attribute__((ext_vector_type(4))) float f32x4;

#define SC_FULL (4096.0f * 1.4426950408889634f)  // scale * log2(e)
#define QSCALE (SC_FULL / 64.0f)
#define KSCALE 64.0f

union f16cv { f16 h; u16 u; };
union pk4 { fp16x2 h2[2]; f16x4 v; };

__device__ __forceinline__ void split2h(float a, u16& hi, u16& lo) {
  f16cv ch, cl;
  ch.h = (f16)a;                 // RNE
  float r = a - (float)ch.h;     // exact
  cl.h = (f16)r;
  hi = ch.u; lo = cl.u;
}

// swizzled ushort offset: row-major stride 64, 8-ush chunks XOR row&7
__device__ __forceinline__ int swz(int row, int chunk) {
  return (row << 6) + ((chunk ^ (row & 7)) << 3);
}

// ---- Fused prepass: K fp32 -> 2 f16 planes (x64); V -> transposed f16 Vt[h][d][s] ----
__global__ void prep_kernel(const float* __restrict__ K, const float* __restrict__ V,
                            u16* __restrict__ Kh, u16* __restrict__ Km,
                            u16* __restrict__ Vt) {
  if (blockIdx.x < 8192) {
    size_t i4 = ((size_t)blockIdx.x * 256 + threadIdx.x) * 4;
    float4 v = *(const float4*)(K + i4);
    u16 h0, l0, h1, l1, h2, l2, h3, l3;
    split2h(v.x * KSCALE, h0, l0);
    split2h(v.y * KSCALE, h1, l1);
    split2h(v.z * KSCALE, h2, l2);
    split2h(v.w * KSCALE, h3, l3);
    *(uint2*)(Kh + i4) = make_uint2((u32)h0 | ((u32)h1 << 16), (u32)h2 | ((u32)h3 << 16));
    *(uint2*)(Km + i4) = make_uint2((u32)l0 | ((u32)l1 << 16), (u32)l2 | ((u32)l3 << 16));
  } else {
    __shared__ float Vf[64 * 65];
    const int idx = blockIdx.x - 8192;
    const int kt = idx & 31, h = idx >> 5;
    const int tid = threadIdx.x;
    const float* V0 = V + ((size_t)h * S_LEN + kt * 64) * 64;
    const int tx = tid & 15, ty = tid >> 4;
#pragma unroll
    for (int p = 0; p < 4; ++p) {
      int r = ty + 16 * p;
      float4 v = *(const float4*)(V0 + r * 64 + tx * 4);
      Vf[r * 65 + 4 * tx + 0] = v.x;
      Vf[r * 65 + 4 * tx + 1] = v.y;
      Vf[r * 65 + 4 * tx + 2] = v.z;
      Vf[r * 65 + 4 * tx + 3] = v.w;
    }
    __syncthreads();
    const int ch = tid & 7, dr = tid >> 3;
#pragma unroll
    for (int p = 0; p < 2; ++p) {
      int d = dr + 32 * p;
      u32 w[4];
#pragma unroll
      for (int i = 0; i < 4; ++i) {
        f16cv a, b;
        a.h = (f16)Vf[(8 * ch + 2 * i) * 65 + d];
        b.h = (f16)Vf[(8 * ch + 2 * i + 1) * 65 + d];
        w[i] = (u32)a.u | ((u32)b.u << 16);
      }
      size_t o = ((size_t)h * 64 + d) * S_LEN + (size_t)kt * 64 + 8 * ch;
      *(uint4*)(Vt + o) = make_uint4(w[0], w[1], w[2], w[3]);
    }
  }
}

// ---- Main fused attention kernel ----
// LDS (ushort units): K0 4096, K1 4096, VT 4096 -> 12288 ush = 24576 B
#define K0_B 0
#define K1_B 4096
#define VT_B 8192
#define LDS_USH 12288

__global__ __launch_bounds__(256, 3)
void attn_mfma_f16(const float* __restrict__ Q, const u16* __restrict__ Kh,
                   const u16* __restrict__ Km, const u16* __restrict__ Vt,
                   float* __restrict__ O) {
  __shared__ __align__(16) u16 lds[LDS_USH];

  const int tid = threadIdx.x;
  const int lane = tid & 63;
  const int wv = tid >> 6;       // 4 waves; wave owns q-rows wv*16 .. wv*16+15
  const int c = lane & 15;
  const int g = lane >> 4;
  const int h = blockIdx.x;      // head fastest: q-tiles of a head share an XCD
  const int qtile = blockIdx.y;

  // ---- load + split Q B-frag, fp32 -> hi/lo f16, scaled ----
  f16x8 aqh[2], aqm[2];
  {
    int qrow = qtile * BM + wv * 16 + c;
    const float* qp = Q + ((size_t)h * S_LEN + qrow) * 64 + g * 8;
#pragma unroll
    for (int ks = 0; ks < 2; ++ks) {
      float4 a = *(const float4*)(qp + ks * 32);
      float4 b = *(const float4*)(qp + ks * 32 + 4);
      float v[8] = {a.x, a.y, a.z, a.w, b.x, b.y, b.z, b.w};
      f16x8 hi, lo;
#pragma unroll
      for (int e = 0; e < 8; ++e) {
        float q = v[e] * QSCALE;
        f16 qh = (f16)q;
        hi[e] = qh;
        lo[e] = (f16)(q - (float)qh);
      }
      aqh[ks] = hi; aqm[ks] = lo;
    }
  }

  f32x4 Oacc[4];
  float mrow = -INFINITY;
  float lrow = 0.f;
#pragma unroll
  for (int t = 0; t < 4; ++t) Oacc[t] = (f32x4){0.f, 0.f, 0.f, 0.f};

  // staging: thread handles row srow, chunks c0 and c0+4 of each plane
  const int srow = tid >> 2;     // 0..63
  const int c0 = tid & 3;
  const int d0a = swz(srow, c0), d0b = swz(srow, c0 + 4);
  const size_t gKbase = ((size_t)h * S_LEN + srow) * 64 + c0 * 8;
  const size_t gVbase = ((size_t)h * 64 + srow) * S_LEN + c0 * 8;

  // prologue: prefetch tile 0 into registers
  uint4 rk0a = *(const uint4*)(Kh + gKbase);
  uint4 rk0b = *(const uint4*)(Kh + gKbase + 32);
  uint4 rk1a = *(const uint4*)(Km + gKbase);
  uint4 rk1b = *(const uint4*)(Km + gKbase + 32);
  uint4 rva  = *(const uint4*)(Vt + gVbase);
  uint4 rvb  = *(const uint4*)(Vt + gVbase + 32);

  for (int kt = 0; kt < KTILES; ++kt) {
    __syncthreads();   // all waves done reading previous tile
    *(uint4*)&lds[K0_B + d0a] = rk0a;
    *(uint4*)&lds[K0_B + d0b] = rk0b;
    *(uint4*)&lds[K1_B + d0a] = rk1a;
    *(uint4*)&lds[K1_B + d0b] = rk1b;
    *(uint4*)&lds[VT_B + d0a] = rva;
    *(uint4*)&lds[VT_B + d0b] = rvb;
    __syncthreads();   // staged tile visible

    // prefetch next tile (overlaps compute)
    if (kt + 1 < KTILES) {
      size_t gK = gKbase + (size_t)(kt + 1) * BN * 64;
      size_t gV = gVbase + (size_t)(kt + 1) * BN;
      rk0a = *(const uint4*)(Kh + gK);
      rk0b = *(const uint4*)(Kh + gK + 32);
      rk1a = *(const uint4*)(Km + gK);
      rk1b = *(const uint4*)(Km + gK + 32);
      rva  = *(const uint4*)(Vt + gV);
      rvb  = *(const uint4*)(Vt + gV + 32);
    }

    // ---- matmul1: S^T = K Q^T (A = K frags from LDS, B = Q in regs) ----
    f32x4 S[4];
#pragma unroll
    for (int t = 0; t < 4; ++t) S[t] = (f32x4){0.f, 0.f, 0.f, 0.f};
    __builtin_amdgcn_s_setprio(1);
#pragma unroll
    for (int ks = 0; ks < 2; ++ks) {
#pragma unroll
      for (int t = 0; t < 4; ++t) {
        int off = swz(16 * t + c, g + 4 * ks);
        f16x8 bh = *(const f16x8*)&lds[K0_B + off];
        f16x8 bm = *(const f16x8*)&lds[K1_B + off];
        S[t] = __builtin_amdgcn_mfma_f32_16x16x32_f16(bh, aqh[ks], S[t], 0, 0, 0);
        S[t] = __builtin_amdgcn_mfma_f32_16x16x32_f16(bm, aqh[ks], S[t], 0, 0, 0);
        S[t] = __builtin_amdgcn_mfma_f32_16x16x32_f16(bh, aqm[ks], S[t], 0, 0, 0);
      }
    }
    __builtin_amdgcn_s_setprio(0);
    // lane (c,g) holds S^T[key=16t+4g+r][qrow=c].

    // ---- online softmax; lane owns q-row c; O^T -> lane-local alpha ----
    f16x4 ap[4];
    {
      float x0 = fmaxf(fmaxf(S[0][0], S[0][1]), fmaxf(S[0][2], S[0][3]));
      float x1 = fmaxf(fmaxf(S[1][0], S[1][1]), fmaxf(S[1][2], S[1][3]));
      float x2 = fmaxf(fmaxf(S[2][0], S[2][1]), fmaxf(S[2][2], S[2][3]));
      float x3 = fmaxf(fmaxf(S[3][0], S[3][1]), fmaxf(S[3][2], S[3][3]));
      float mx = fmaxf(fmaxf(x0, x1), fmaxf(x2, x3));
      mx = fmaxf(mx, __shfl_xor(mx, 16));
      mx = fmaxf(mx, __shfl_xor(mx, 32));
      float mnew = fmaxf(mrow, mx);
      float a = exp2f(mrow - mnew);   // -inf first iter -> 0
      mrow = mnew;
      float ps = 0.f;
#pragma unroll
      for (int t = 0; t < 4; ++t) {
        float p0 = exp2f(S[t][0] - mnew);
        float p1 = exp2f(S[t][1] - mnew);
        float p2 = exp2f(S[t][2] - mnew);
        float p3 = exp2f(S[t][3] - mnew);
        ps += (p0 + p1) + (p2 + p3);
        pk4 w;
        w.h2[0] = __builtin_amdgcn_cvt_pkrtz(p0, p1);
        w.h2[1] = __builtin_amdgcn_cvt_pkrtz(p2, p3);
        ap[t] = w.v;
      }
      lrow = lrow * a + ps;
      // O^T layout: this lane's whole Oacc belongs to q-row c -> lane-local
#pragma unroll
      for (int nt = 0; nt < 4; ++nt)
#pragma unroll
        for (int r = 0; r < 4; ++r) Oacc[nt][r] *= a;
    }

    // ---- PV: O^T += V^T P^T via 16x16x16 (B-frag k=4g+e == S^T layout) ----
    __builtin_amdgcn_s_setprio(1);
#pragma unroll
    for (int nt = 0; nt < 4; ++nt) {
      const int rv = 16 * nt + c;
      const int rb = VT_B + rv * 64 + 4 * (g & 1);
      const int r7 = rv & 7;
#pragma unroll
      for (int t = 0; t < 4; ++t) {
        f16x4 bv = *(const f16x4*)&lds[rb + (((2 * t + (g >> 1)) ^ r7) << 3)];
        Oacc[nt] = __builtin_amdgcn_mfma_f32_16x16x16f16(bv, ap[t], Oacc[nt], 0, 0, 0);
      }
    }
    __builtin_amdgcn_s_setprio(0);
    // lane (c,g) holds O^T[d=16nt+4g+r][q-row=c] in Oacc[nt][r].
  }

  // ---- epilogue: reduce l across g-lanes, lane-local 1/l, float4 stores ----
  {
    float l = lrow;
    l += __shfl_xor(l, 16);
    l += __shfl_xor(l, 32);
    float linv = 1.0f / l;
    int q = qtile * BM + wv * 16 + c;
    float* op = O + ((size_t)h * S_LEN + q) * 64 + 4 * g;
#pragma unroll
    for (int nt = 0; nt < 4; ++nt) {
      float4 o;
      o.x = Oacc[nt][0] * linv;
      o.y = Oacc[nt][1] * linv;
      o.z = Oacc[nt][2] * linv;
      o.w = Oacc[nt][3] * linv;
      *(float4*)(op + 16 * nt) = o;
    }
  }
}

// ---- Fallback: fp32 vector kernel (used only if ws too small) ----
#define LSTR 68
__global__ __launch_bounds__(256, 2)
void attn_fp32_kernel(const float* __restrict__ Q, const float* __restrict__ K,
                      const float* __restrict__ V, float* __restrict__ O) {
  __shared__ float Qs[64][LSTR];
  __shared__ float Ks[64][LSTR];
  __shared__ float Vs[64][LSTR];
  __shared__ float Ps[64][LSTR];
  const int tid = threadIdx.x;
  const int tx = tid & 15, ty = tid >> 4;
  const int qtile = blockIdx.x, head = blockIdx.y;
  const long hoff = (long)head * S_LEN * D_DIM;
  const float* Qp = Q + hoff + (long)qtile * 64 * D_DIM;
  const float* Kp = K + hoff;
  const float* Vp = V + hoff;
  float* Op = O + hoff + (long)qtile * 64 * D_DIM;
  {
    const int cc = tx * 4;
#pragma unroll
    for (int p = 0; p < 4; ++p) {
      const int r = ty + p * 16;
      *(float4*)(&Qs[r][cc]) = *(const float4*)(Qp + r * D_DIM + cc);
    }
  }
  float m_i[4], l_i[4];
  float4 o_acc[4];
#pragma unroll
  for (int i = 0; i < 4; ++i) {
    m_i[i] = -INFINITY; l_i[i] = 0.0f;
    o_acc[i] = make_float4(0.f, 0.f, 0.f, 0.f);
  }
  const float SCALE = 4096.0f;
  const float LOG2E = 1.4426950408889634f;
  for (int kt = 0; kt < S_LEN / 64; ++kt) {
    {
      const int cc = tx * 4;
      const float* Kt = Kp + kt * 64 * D_DIM;
      const float* Vv = Vp + kt * 64 * D_DIM;
#pragma unroll
      for (int p = 0; p < 4; ++p) {
        const int r = ty + p * 16;
        *(float4*)(&Ks[r][cc]) = *(const float4*)(Kt + r * D_DIM + cc);
        *(float4*)(&Vs[r][cc]) = *(const float4*)(Vv + r * D_DIM + cc);
      }
    }
    __syncthreads();
    float s[4][4];
#pragma unroll
    for (int i = 0; i < 4; ++i)
#pragma unroll
      for (int j = 0; j < 4; ++j) s[i][j] = 0.0f;
#pragma unroll
    for (int d = 0; d < D_DIM; d += 4) {
      float4 q4[4], k4[4];
#pragma unroll
      for (int i = 0; i < 4; ++i) q4[i] = *(const float4*)(&Qs[ty * 4 + i][d]);
#pragma unroll
      for (int j = 0; j < 4; ++j) k4[j] = *(const float4*)(&Ks[tx + 16 * j][d]);
#pragma unroll
      for (int i = 0; i < 4; ++i)
#pragma unroll
        for (int j = 0; j < 4; ++j) {
          s[i][j] += q4[i].x * k4[j].x; s[i][j] += q4[i].y * k4[j].y;
          s[i][j] += q4[i].z * k4[j].z; s[i][j] += q4[i].w * k4[j].w;
        }
    }
#pragma unroll
    for (int i = 0; i < 4; ++i) {
#pragma unroll
      for (int j = 0; j < 4; ++j) s[i][j] *= SCALE;
      float rm = fmaxf(fmaxf(s[i][0], s[i][1]), fmaxf(s[i][2], s[i][3]));
#pragma unroll
      for (int off = 8; off >= 1; off >>= 1) rm = fmaxf(rm, __shfl_xor(rm, off));
      const float mnew = fmaxf(m_i[i], rm);
      const float alpha = exp2f((m_i[i] - mnew) * LOG2E);
      float rs = 0.0f;
#pragma unroll
      for (int j = 0; j < 4; ++j) {
        const float p = exp2f((s[i][j] - mnew) * LOG2E);
        s[i][j] = p; rs += p;
      }
#pragma unroll
      for (int off = 8; off >= 1; off >>= 1) rs += __shfl_xor(rs, off);
      l_i[i] = l_i[i] * alpha + rs;
      m_i[i] = mnew;
      o_acc[i].x *= alpha; o_acc[i].y *= alpha; o_acc[i].z *= alpha; o_acc[i].w *= alpha;
      const int mm = ty * 4 + i;
      Ps[mm][tx] = s[i][0]; Ps[mm][tx + 16] = s[i][1];
      Ps[mm][tx + 32] = s[i][2]; Ps[mm][tx + 48] = s[i][3];
    }
    __syncthreads();
#pragma unroll
    for (int k = 0; k < 64; k += 4) {
      float4 p4[4], v4[4];
#pragma unroll
      for (int i = 0; i < 4; ++i) p4[i] = *(const float4*)(&Ps[ty * 4 + i][k]);
#pragma unroll
      for (int kk = 0; kk < 4; ++kk) v4[kk] = *(const float4*)(&Vs[k + kk][tx * 4]);
#pragma unroll
      for (int i = 0; i < 4; ++i) {
        o_acc[i].x += p4[i].x * v4[0].x + p4[i].y * v4[1].x + p4[i].z * v4[2].x + p4[i].w * v4[3].x;
        o_acc[i].y += p4[i].x * v4[0].y + p4[i].y * v4[1].y + p4[i].z * v4[2].y + p4[i].w * v4[3].y;
        o_acc[i].z += p4[i].x * v4[0].z + p4[i].y * v4[1].z + p4[i].z * v4[2].z + p4[i].w * v4[3].z;
        o_acc[i].w += p4[i].x * v4[0].w + p4[i].y * v4[1].w + p4[i].z * v4[2].w + p4[i].w * v4[3].w;
      }
    }
    __syncthreads();
  }
#pragma unroll
  for (int i = 0; i < 4; ++i) {
    const float inv = 1.0f / l_i[i];
    o_acc[i].x *= inv; o_acc[i].y *= inv; o_acc[i].z *= inv; o_acc[i].w *= inv;
    *(float4*)(Op + (ty * 4 + i) * D_DIM + tx * 4) = o_acc[i];
  }
}

extern "C" void kernel_launch(void* const* d_in, const int* in_sizes, int n_in,
                              void* d_out, int out_size, void* d_ws, size_t ws_size,
                              hipStream_t stream) {
  const float* Q = (const float*)d_in[0];
  const float* K = (const float*)d_in[1];
  const float* V = (const float*)d_in[2];
  float* O = (float*)d_out;

  const size_t P = (size_t)NH * S_LEN * D_DIM;  // 8388608 per plane
  const size_t need = 3 * P * sizeof(u16);      // 50.3 MB

  if (ws_size >= need) {
    u16* w = (u16*)d_ws;
    u16 *Kh = w, *Km = w + P, *Vt = w + 2 * P;
    prep_kernel<<<8192 + 2048, 256, 0, stream>>>(K, V, Kh, Km, Vt);
    attn_mfma_f16<<<dim3(NH, QTILES), 256, 0, stream>>>(Q, Kh, Km, Vt, O);
  } else {
    attn_fp32_kernel<<<dim3(S_LEN / 64, NH), 256, 0, stream>>>(Q, K, V, O);
  }
}

// Round 8
// 305.214 us; speedup vs baseline: 1.0243x; 1.0243x over previous
//
#include <hip/hip_runtime.h>
#include <math.h>

// B=4,H=16 (NH=64), S=2048, D=64, fp32 in/out.
// scores = (Q@K^T)*4096, softmax, @V.
// f16 2-plane split: S = qh*kh + qh*km(lo) + qm(lo)*kh (err ~2^-22),
// PV = f16(P) x f16(V). Q scaled by 4096*log2e/64 (in-kernel split),
// K by 64 (prepass), V transposed to f16 (prepass, fused into one launch).
// Round 14: r6 base (BM=128, register staging; 207us verified) + 3 levers:
//  (1) staging remap row=tid>>3,chunk=tid&7: quarter-wave covers all 8
//      chunk-columns -> 2-way (free) LDS writes vs 4-way before.
//  (2) double-buffered LDS (2x12288 ush = 49152B), ONE barrier per tile:
//      write regs->buf[(kt+1)&1] overlaps compute on buf[kt&1]; buffer
//      being written was last read before the barrier just crossed.
//      Regs cap residency (~2 blocks) so LDS doubling is free.
//  (3) T13 defer-max (verified r3): skip alpha/rescale+max-update unless
//      __all(mx - mrow <= 8).
// Register-direct PV via mfma_f32_16x16x16f16 (B-frag k=4g+e == S^T layout,
// P never touches LDS); O^T accumulator (lane-local alpha, float4 stores).

#define S_LEN 2048
#define D_DIM 64
#define NH 64
#define BM 128
#define BN 64
#define QTILES (S_LEN / BM)   // 16
#define KTILES (S_LEN / BN)   // 32

typedef unsigned short u16;
typedef unsigned int u32;
typedef _Float16 f16;
typedef __attribute__((ext_vector_type(4))) _Float16 f16x4;
typedef __attribute__((ext_vector_type(8))) _Float16 f16x8;
typedef __attribute__((ext_vector_type(2))) __fp16 fp16x2;
typedef __attribute__((ext_vector_type(4))) float f32x4;

#define SC_FULL (4096.0f * 1.4426950408889634f)  // scale * log2(e)
#define QSCALE (SC_FULL / 64.0f)
#define KSCALE 64.0f

union f16cv { f16 h; u16 u; };
union pk4 { fp16x2 h2[2]; f16x4 v; };

__device__ __forceinline__ void split2h(float a, u16& hi, u16& lo) {
  f16cv ch, cl;
  ch.h = (f16)a;                 // RNE
  float r = a - (float)ch.h;     // exact
  cl.h = (f16)r;
  hi = ch.u; lo = cl.u;
}

// swizzled ushort offset: row-major stride 64, 8-ush chunks XOR row&7
__device__ __forceinline__ int swz(int row, int chunk) {
  return (row << 6) + ((chunk ^ (row & 7)) << 3);
}

// ---- Fused prepass: K fp32 -> 2 f16 planes (x64); V -> transposed f16 Vt[h][d][s] ----
__global__ void prep_kernel(const float* __restrict__ K, const float* __restrict__ V,
                            u16* __restrict__ Kh, u16* __restrict__ Km,
                            u16* __restrict__ Vt) {
  if (blockIdx.x < 8192) {
    size_t i4 = ((size_t)blockIdx.x * 256 + threadIdx.x) * 4;
    float4 v = *(const float4*)(K + i4);
    u16 h0, l0, h1, l1, h2, l2, h3, l3;
    split2h(v.x * KSCALE, h0, l0);
    split2h(v.y * KSCALE, h1, l1);
    split2h(v.z * KSCALE, h2, l2);
    split2h(v.w * KSCALE, h3, l3);
    *(uint2*)(Kh + i4) = make_uint2((u32)h0 | ((u32)h1 << 16), (u32)h2 | ((u32)h3 << 16));
    *(uint2*)(Km + i4) = make_uint2((u32)l0 | ((u32)l1 << 16), (u32)l2 | ((u32)l3 << 16));
  } else {
    __shared__ float Vf[64 * 65];
    const int idx = blockIdx.x - 8192;
    const int kt = idx & 31, h = idx >> 5;
    const int tid = threadIdx.x;
    const float* V0 = V + ((size_t)h * S_LEN + kt * 64) * 64;
    const int tx = tid & 15, ty = tid >> 4;
#pragma unroll
    for (int p = 0; p < 4; ++p) {
      int r = ty + 16 * p;
      float4 v = *(const float4*)(V0 + r * 64 + tx * 4);
      Vf[r * 65 + 4 * tx + 0] = v.x;
      Vf[r * 65 + 4 * tx + 1] = v.y;
      Vf[r * 65 + 4 * tx + 2] = v.z;
      Vf[r * 65 + 4 * tx + 3] = v.w;
    }
    __syncthreads();
    const int ch = tid & 7, dr = tid >> 3;
#pragma unroll
    for (int p = 0; p < 2; ++p) {
      int d = dr + 32 * p;
      u32 w[4];
#pragma unroll
      for (int i = 0; i < 4; ++i) {
        f16cv a, b;
        a.h = (f16)Vf[(8 * ch + 2 * i) * 65 + d];
        b.h = (f16)Vf[(8 * ch + 2 * i + 1) * 65 + d];
        w[i] = (u32)a.u | ((u32)b.u << 16);
      }
      size_t o = ((size_t)h * 64 + d) * S_LEN + (size_t)kt * 64 + 8 * ch;
      *(uint4*)(Vt + o) = make_uint4(w[0], w[1], w[2], w[3]);
    }
  }
}

// ---- Main fused attention kernel ----
// LDS: two buffers of {K0 4096, K1 4096, VT 4096} ush -> 24576 ush = 49152 B
#define K0_B 0
#define K1_B 4096
#define VT_B 8192
#define BUF_USH 12288
#define LDS_USH 24576

__global__ __launch_bounds__(256, 3)
void attn_mfma_f16(const float* __restrict__ Q, const u16* __restrict__ Kh,
                   const u16* __restrict__ Km, const u16* __restrict__ Vt,
                   float* __restrict__ O) {
  __shared__ __align__(16) u16 lds[LDS_USH];

  const int tid = threadIdx.x;
  const int lane = tid & 63;
  const int wv = tid >> 6;       // 4 waves; wave owns q-rows wv*32 .. wv*32+31
  const int c = lane & 15;
  const int g = lane >> 4;
  const int h = blockIdx.x;      // head fastest: q-tiles of a head share an XCD
  const int qtile = blockIdx.y;

  // ---- load + split Q B-frags (2 m-tiles), fp32 -> hi/lo f16, scaled ----
  f16x8 aqh[2][2], aqm[2][2];
#pragma unroll
  for (int m = 0; m < 2; ++m) {
    int qrow = qtile * BM + wv * 32 + m * 16 + c;
    const float* qp = Q + ((size_t)h * S_LEN + qrow) * 64 + g * 8;
#pragma unroll
    for (int ks = 0; ks < 2; ++ks) {
      float4 a = *(const float4*)(qp + ks * 32);
      float4 b = *(const float4*)(qp + ks * 32 + 4);
      float v[8] = {a.x, a.y, a.z, a.w, b.x, b.y, b.z, b.w};
      f16x8 hi, lo;
#pragma unroll
      for (int e = 0; e < 8; ++e) {
        float q = v[e] * QSCALE;
        f16 qh = (f16)q;
        hi[e] = qh;
        lo[e] = (f16)(q - (float)qh);
      }
      aqh[m][ks] = hi; aqm[m][ks] = lo;
    }
  }

  f32x4 Oacc[2][4];
  float mrow[2] = {-INFINITY, -INFINITY};
  float lrow[2] = {0.f, 0.f};
#pragma unroll
  for (int m = 0; m < 2; ++m)
#pragma unroll
    for (int t = 0; t < 4; ++t) Oacc[m][t] = (f32x4){0.f, 0.f, 0.f, 0.f};

  // ---- staging: thread covers rows rs and rs+32, chunk cl of each plane ----
  // Quarter-wave (16 lanes) = 2 rows x 8 chunks -> all 8 chunk-columns hit,
  // 2 lanes per bank group -> conflict-free b128 writes. Global loads are
  // 128B-contiguous per 8 lanes.
  const int rs = tid >> 3;       // 0..31
  const int cl = tid & 7;
  const int d0 = swz(rs, cl);    // row rs+32 lands at d0 + 2048
  const size_t gK0 = ((size_t)h * S_LEN + rs) * 64 + cl * 8;
  const size_t gV0 = ((size_t)h * 64 + rs) * S_LEN + cl * 8;

  uint4 rk0a, rk0b, rk1a, rk1b, rva, rvb;
  auto load6 = [&](int kt) {
    size_t gK = gK0 + (size_t)kt * 4096;
    size_t gV = gV0 + (size_t)kt * 64;
    rk0a = *(const uint4*)(Kh + gK);
    rk0b = *(const uint4*)(Kh + gK + 2048);
    rk1a = *(const uint4*)(Km + gK);
    rk1b = *(const uint4*)(Km + gK + 2048);
    rva  = *(const uint4*)(Vt + gV);
    rvb  = *(const uint4*)(Vt + gV + (size_t)32 * S_LEN);
  };
  auto write6 = [&](int b) {
    u16* lb = lds + b * BUF_USH;
    *(uint4*)&lb[K0_B + d0] = rk0a;
    *(uint4*)&lb[K0_B + d0 + 2048] = rk0b;
    *(uint4*)&lb[K1_B + d0] = rk1a;
    *(uint4*)&lb[K1_B + d0 + 2048] = rk1b;
    *(uint4*)&lb[VT_B + d0] = rva;
    *(uint4*)&lb[VT_B + d0 + 2048] = rvb;
  };

  // prologue: tile 0 -> buf0; tile 1 -> regs
  load6(0);
  write6(0);
  load6(1);
  __syncthreads();

  for (int kt = 0; kt < KTILES; ++kt) {
    const int cb = (kt & 1) * BUF_USH;

    // writes overlap compute: target buffer's last readers finished before
    // the barrier we just crossed (iter kt-1 read buf[(kt-1)&1]).
    if (kt + 1 < KTILES) write6((kt + 1) & 1);
    if (kt + 2 < KTILES) load6(kt + 2);

    // ---- matmul1: S^T = K Q^T (A = K frags shared across m, B = Q in regs) ----
    f32x4 S[2][4];
#pragma unroll
    for (int m = 0; m < 2; ++m)
#pragma unroll
      for (int t = 0; t < 4; ++t) S[m][t] = (f32x4){0.f, 0.f, 0.f, 0.f};
    __builtin_amdgcn_s_setprio(1);
#pragma unroll
    for (int ks = 0; ks < 2; ++ks) {
#pragma unroll
      for (int t = 0; t < 4; ++t) {
        int off = cb + swz(16 * t + c, g + 4 * ks);
        f16x8 bh = *(const f16x8*)&lds[K0_B + off];
        f16x8 bm = *(const f16x8*)&lds[K1_B + off];
#pragma unroll
        for (int m = 0; m < 2; ++m) {
          S[m][t] = __builtin_amdgcn_mfma_f32_16x16x32_f16(bh, aqh[m][ks], S[m][t], 0, 0, 0);
          S[m][t] = __builtin_amdgcn_mfma_f32_16x16x32_f16(bm, aqh[m][ks], S[m][t], 0, 0, 0);
          S[m][t] = __builtin_amdgcn_mfma_f32_16x16x32_f16(bh, aqm[m][ks], S[m][t], 0, 0, 0);
        }
      }
    }
    __builtin_amdgcn_s_setprio(0);
    // lane (c,g) holds S^T[key=16t+4g+r][qrow=c] for m-tile m.

    // ---- online softmax; lane owns q-row c; T13 defer-max ----
    f16x4 ap[2][4];
#pragma unroll
    for (int m = 0; m < 2; ++m) {
      float x0 = fmaxf(fmaxf(S[m][0][0], S[m][0][1]), fmaxf(S[m][0][2], S[m][0][3]));
      float x1 = fmaxf(fmaxf(S[m][1][0], S[m][1][1]), fmaxf(S[m][1][2], S[m][1][3]));
      float x2 = fmaxf(fmaxf(S[m][2][0], S[m][2][1]), fmaxf(S[m][2][2], S[m][2][3]));
      float x3 = fmaxf(fmaxf(S[m][3][0], S[m][3][1]), fmaxf(S[m][3][2], S[m][3][3]));
      float mx = fmaxf(fmaxf(x0, x1), fmaxf(x2, x3));
      mx = fmaxf(mx, __shfl_xor(mx, 16));
      mx = fmaxf(mx, __shfl_xor(mx, 32));
      if (!__all(mx - mrow[m] <= 8.0f)) {   // rescale only on real max growth
        float mnew = fmaxf(mrow[m], mx);
        float a = exp2f(mrow[m] - mnew);    // -inf first iter -> 0
        mrow[m] = mnew;
        lrow[m] *= a;
#pragma unroll
        for (int nt = 0; nt < 4; ++nt)
#pragma unroll
          for (int r = 0; r < 4; ++r) Oacc[m][nt][r] *= a;
      }
      float ps = 0.f;
#pragma unroll
      for (int t = 0; t < 4; ++t) {
        float p0 = exp2f(S[m][t][0] - mrow[m]);
        float p1 = exp2f(S[m][t][1] - mrow[m]);
        float p2 = exp2f(S[m][t][2] - mrow[m]);
        float p3 = exp2f(S[m][t][3] - mrow[m]);
        ps += (p0 + p1) + (p2 + p3);
        pk4 w;
        w.h2[0] = __builtin_amdgcn_cvt_pkrtz(p0, p1);
        w.h2[1] = __builtin_amdgcn_cvt_pkrtz(p2, p3);
        ap[m][t] = w.v;
      }
      lrow[m] += ps;
    }

    // ---- PV: O^T += V^T P^T via 16x16x16 (B-frag k=4g+e == S^T layout) ----
    __builtin_amdgcn_s_setprio(1);
#pragma unroll
    for (int nt = 0; nt < 4; ++nt) {
      const int rv = 16 * nt + c;
      const int rb = cb + VT_B + rv * 64 + 4 * (g & 1);
      const int r7 = rv & 7;
#pragma unroll
      for (int t = 0; t < 4; ++t) {
        f16x4 bv = *(const f16x4*)&lds[rb + (((2 * t + (g >> 1)) ^ r7) << 3)];
#pragma unroll
        for (int m = 0; m < 2; ++m)
          Oacc[m][nt] = __builtin_amdgcn_mfma_f32_16x16x16f16(bv, ap[m][t], Oacc[m][nt], 0, 0, 0);
      }
    }
    __builtin_amdgcn_s_setprio(0);
    // lane (c,g) holds O^T[d=16nt+4g+r][q-row=c] in Oacc[m][nt][r].

    __syncthreads();   // next iter may overwrite buf[(kt+1)&1]... wait: (kt+2)
  }

  // ---- epilogue: reduce l across g-lanes, lane-local 1/l, float4 stores ----
#pragma unroll
  for (int m = 0; m < 2; ++m) {
    float l = lrow[m];
    l += __shfl_xor(l, 16);
    l += __shfl_xor(l, 32);
    float linv = 1.0f / l;
    int q = qtile * BM + wv * 32 + m * 16 + c;
    float* op = O + ((size_t)h * S_LEN + q) * 64 + 4 * g;
#pragma unroll
    for (int nt = 0; nt < 4; ++nt) {
      float4 o;
      o.x = Oacc[m][nt][0] * linv;
      o.y = Oacc[m][nt][1] * linv;
      o.z = Oacc[m][nt][2] * linv;
      o.w = Oacc[m][nt][3] * linv;
      *(float4*)(op + 16 * nt) = o;
    }
  }
}

// ---- Fallback: fp32 vector kernel (used only if ws too small) ----
#define LSTR 68
__global__ __launch_bounds__(256, 2)
void attn_fp32_kernel(const float* __restrict__ Q, const float* __restrict__ K,
                      const float* __restrict__ V, float* __restrict__ O) {
  __shared__ float Qs[64][LSTR];
  __shared__ float Ks[64][LSTR];
  __shared__ float Vs[64][LSTR];
  __shared__ float Ps[64][LSTR];
  const int tid = threadIdx.x;
  const int tx = tid & 15, ty = tid >> 4;
  const int qtile = blockIdx.x, head = blockIdx.y;
  const long hoff = (long)head * S_LEN * D_DIM;
  const float* Qp = Q + hoff + (long)qtile * 64 * D_DIM;
  const float* Kp = K + hoff;
  const float* Vp = V + hoff;
  float* Op = O + hoff + (long)qtile * 64 * D_DIM;
  {
    const int cc = tx * 4;
#pragma unroll
    for (int p = 0; p < 4; ++p) {
      const int r = ty + p * 16;
      *(float4*)(&Qs[r][cc]) = *(const float4*)(Qp + r * D_DIM + cc);
    }
  }
  float m_i[4], l_i[4];
  float4 o_acc[4];
#pragma unroll
  for (int i = 0; i < 4; ++i) {
    m_i[i] = -INFINITY; l_i[i] = 0.0f;
    o_acc[i] = make_float4(0.f, 0.f, 0.f, 0.f);
  }
  const float SCALE = 4096.0f;
  const float LOG2E = 1.4426950408889634f;
  for (int kt = 0; kt < S_LEN / 64; ++kt) {
    {
      const int cc = tx * 4;
      const float* Kt = Kp + kt * 64 * D_DIM;
      const float* Vv = Vp + kt * 64 * D_DIM;
#pragma unroll
      for (int p = 0; p < 4; ++p) {
        const int r = ty + p * 16;
        *(float4*)(&Ks[r][cc]) = *(const float4*)(Kt + r * D_DIM + cc);
        *(float4*)(&Vs[r][cc]) = *(const float4*)(Vv + r * D_DIM + cc);
      }
    }
    __syncthreads();
    float s[4][4];
#pragma unroll
    for (int i = 0; i < 4; ++i)
#pragma unroll
      for (int j = 0; j < 4; ++j) s[i][j] = 0.0f;
#pragma unroll
    for (int d = 0; d < D_DIM; d += 4) {
      float4 q4[4], k4[4];
#pragma unroll
      for (int i = 0; i < 4; ++i) q4[i] = *(const float4*)(&Qs[ty * 4 + i][d]);
#pragma unroll
      for (int j = 0; j < 4; ++j) k4[j] = *(const float4*)(&Ks[tx + 16 * j][d]);
#pragma unroll
      for (int i = 0; i < 4; ++i)
#pragma unroll
        for (int j = 0; j < 4; ++j) {
          s[i][j] += q4[i].x * k4[j].x; s[i][j] += q4[i].y * k4[j].y;
          s[i][j] += q4[i].z * k4[j].z; s[i][j] += q4[i].w * k4[j].w;
        }
    }
#pragma unroll
    for (int i = 0; i < 4; ++i) {
#pragma unroll
      for (int j = 0; j < 4; ++j) s[i][j] *= SCALE;
      float rm = fmaxf(fmaxf(s[i][0], s[i][1]), fmaxf(s[i][2], s[i][3]));
#pragma unroll
      for (int off = 8; off >= 1; off >>= 1) rm = fmaxf(rm, __shfl_xor(rm, off));
      const float mnew = fmaxf(m_i[i], rm);
      const float alpha = exp2f((m_i[i] - mnew) * LOG2E);
      float rs = 0.0f;
#pragma unroll
      for (int j = 0; j < 4; ++j) {
        const float p = exp2f((s[i][j] - mnew) * LOG2E);
        s[i][j] = p; rs += p;
      }
#pragma unroll
      for (int off = 8; off >= 1; off >>= 1) rs += __shfl_xor(rs, off);
      l_i[i] = l_i[i] * alpha + rs;
      m_i[i] = mnew;
      o_acc[i].x *= alpha; o_acc[i].y *= alpha; o_acc[i].z *= alpha; o_acc[i].w *= alpha;
      const int mm = ty * 4 + i;
      Ps[mm][tx] = s[i][0]; Ps[mm][tx + 16] = s[i][1];
      Ps[mm][tx + 32] = s[i][2]; Ps[mm][tx + 48] = s[i][3];
    }
    __syncthreads();
#pragma unroll
    for (int k = 0; k < 64; k += 4) {
      float4 p4[4], v4[4];
#pragma unroll
      for (int i = 0; i < 4; ++i) p4[i] = *(const float4*)(&Ps[ty * 4 + i][k]);
#pragma unroll
      for (int kk = 0; kk < 4; ++kk) v4[kk] = *(const float4*)(&Vs[k + kk][tx * 4]);
#pragma unroll
      for (int i = 0; i < 4; ++i) {
        o_acc[i].x += p4[i].x * v4[0].x + p4[i].y * v4[1].x + p4[i].z * v4[2].x + p4[i].w * v4[3].x;
        o_acc[i].y += p4[i].x * v4[0].y + p4[i].y * v4[1].y + p4[i].z * v4[2].y + p4[i].w * v4[3].y;
        o_acc[i].z += p4[i].x * v4[0].z + p4[i].y * v4[1].z + p4[i].z * v4[2].z + p4[i].w * v4[3].z;
        o_acc[i].w += p4[i].x * v4[0].w + p4[i].y * v4[1].w + p4[i].z * v4[2].w + p4[i].w * v4[3].w;
      }
    }
    __syncthreads();
  }
#pragma unroll
  for (int i = 0; i < 4; ++i) {
    const float inv = 1.0f / l_i[i];
    o_acc[i].x *= inv; o_acc[i].y *= inv; o_acc[i].z *= inv; o_acc[i].w *= inv;
    *(float4*)(Op + (ty * 4 + i) * D_DIM + tx * 4) = o_acc[i];
  }
}

extern "C" void kernel_launch(void* const* d_in, const int* in_sizes, int n_in,
                              void* d_out, int out_size, void* d_ws, size_t ws_size,
                              hipStream_t stream) {
  const float* Q = (const float*)d_in[0];
  const float* K = (const float*)d_in[1];
  const float* V = (const float*)d_in[2];
  float* O = (float*)d_out;

  const size_t P = (size_t)NH * S_LEN * D_DIM;  // 8388608 per plane
  const size_t need = 3 * P * sizeof(u16);      // 50.3 MB

  if (ws_size >= need) {
    u16* w = (u16*)d_ws;
    u16 *Kh = w, *Km = w + P, *Vt = w + 2 * P;
    prep_kernel<<<8192 + 2048, 256, 0, stream>>>(K, V, Kh, Km, Vt);
    attn_mfma_f16<<<dim3(NH, QTILES), 256, 0, stream>>>(Q, Kh, Km, Vt, O);
  } else {
    attn_fp32_kernel<<<dim3(S_LEN / 64, NH), 256, 0, stream>>>(Q, K, V, O);
  }
}